// Round 6
// baseline (499.731 us; speedup 1.0000x reference)
//
#include <hip/hip_runtime.h>

// out[t,b,n] = 1 iff any spike in window [t-duration+1, t].
// R6: two-phase via byte-packed bitmask bm8[tq][c4] (uint32: byte j =
// col 4*c4+j, bit r = t = tq*8+r; 8.4 MB in d_ws). BOTH passes sweep
// memory IN ORDER with a compact active front (the variable separating
// the 6.5 TB/s fill kernel from our 2.4-3 TB/s kernels):
//   K1: work items (tq-major, stripe-minor) grid-strided -> front is a
//       contiguous ~32 MB window. 8 independent loads/thread, 1-word state.
//   K2: linear grid-stride over flat out; 14 clamped L2-hit word loads,
//       uniform scalar masks, nontemporal float4 stores.

#define T_TOTAL 2048
#define M_COLS  (16 * 2048)
#define M4      8192            // float4 groups per row
#define TQ      (T_TOTAL / 8)   // 256 byte-rows
#define GRID    1024

typedef float f32x4 __attribute__((ext_vector_type(4)));

// ---- K1: pack 8 t-rows -> one uint32 per 4 cols ----
__global__ __launch_bounds__(256) void pack8(
    const float4* __restrict__ x,     // [T][M4]
    unsigned* __restrict__ bm8)       // [TQ][M4]
{
    const int tid = threadIdx.x;
    for (int w = blockIdx.x; w < TQ * 32; w += GRID) {
        const int tq = w >> 5;                     // byte-row
        const int c4 = ((w & 31) << 8) + tid;      // 0..M4-1
        const float4* xp = x + (size_t)tq * 8 * M4 + c4;

        float4 v[8];
        #pragma unroll
        for (int r = 0; r < 8; ++r) v[r] = xp[(size_t)r * M4];  // 8 in flight

        unsigned s = 0;
        #pragma unroll
        for (int r = 0; r < 8; ++r) {
            s |= (v[r].x != 0.0f ? 1u : 0u) << r;
            s |= (v[r].y != 0.0f ? 1u : 0u) << (8 + r);
            s |= (v[r].z != 0.0f ? 1u : 0u) << (16 + r);
            s |= (v[r].w != 0.0f ? 1u : 0u) << (24 + r);
        }
        bm8[(size_t)tq * M4 + c4] = s;
    }
}

// ---- K2: windowed OR over <=14 byte-rows -> fp32, linear write ----
__global__ __launch_bounds__(256) void unpack_or(
    const unsigned* __restrict__ bm8, // [TQ][M4]
    const int* __restrict__ dur_p,
    float* __restrict__ out)          // flat [T*M_COLS]
{
    const int duration = dur_p[0];    // uniform
    const int tid = threadIdx.x;

    for (int ci = blockIdx.x; ci < T_TOTAL * 32; ci += GRID) {
        const int t  = ci >> 5;                    // uniform per chunk
        const int c4 = ((ci & 31) << 8) + tid;     // 0..M4-1
        int L = t - (duration - 1); if (L < 0) L = 0;
        const int tq = t >> 3, Lq = L >> 3;

        unsigned acc = 0;
        if (tq - Lq <= 13) {
            unsigned wv[14];
            #pragma unroll
            for (int j = 0; j < 14; ++j) {         // 14 independent clamped loads
                int wi = Lq + j; if (wi > TQ - 1) wi = TQ - 1;
                wv[j] = bm8[(size_t)wi * M4 + c4];
            }
            #pragma unroll
            for (int j = 0; j < 14; ++j) {
                const int wi = Lq + j;             // uniform -> SALU masks
                int lo = L - wi * 8; if (lo < 0) lo = 0;
                int hi = t - wi * 8; if (hi > 7) hi = 7;
                unsigned m8 = (hi >= lo) ? (((2u << hi) - 1u) & ~((1u << lo) - 1u)) : 0u;
                acc |= wv[j] & (m8 * 0x01010101u);
            }
        } else {
            // generic fallback for duration > ~107 (never taken at 100)
            for (int wi = Lq; wi <= tq; ++wi) {
                int lo = L - wi * 8; if (lo < 0) lo = 0;
                int hi = t - wi * 8; if (hi > 7) hi = 7;
                unsigned m8 = (((2u << hi) - 1u) & ~((1u << lo) - 1u));
                acc |= bm8[(size_t)wi * M4 + c4] & (m8 * 0x01010101u);
            }
        }

        f32x4 o;
        o.x = (acc & 0x000000ffu) ? 1.0f : 0.0f;
        o.y = (acc & 0x0000ff00u) ? 1.0f : 0.0f;
        o.z = (acc & 0x00ff0000u) ? 1.0f : 0.0f;
        o.w = (acc & 0xff000000u) ? 1.0f : 0.0f;
        __builtin_nontemporal_store(
            o, (f32x4*)(out + (size_t)ci * 1024 + (size_t)tid * 4));
    }
}

extern "C" void kernel_launch(void* const* d_in, const int* in_sizes, int n_in,
                              void* d_out, int out_size, void* d_ws, size_t ws_size,
                              hipStream_t stream) {
    const float4* x     = (const float4*)d_in[0];
    const int*    dur_p = (const int*)d_in[1];
    float*        out   = (float*)d_out;
    unsigned*     bm8   = (unsigned*)d_ws;   // TQ*M4*4 = 8.4 MB scratch

    pack8<<<GRID, 256, 0, stream>>>(x, bm8);
    unpack_or<<<GRID, 256, 0, stream>>>(bm8, dur_p, out);
}